// Round 5
// baseline (232.838 us; speedup 1.0000x reference)
//
#include <hip/hip_runtime.h>

#define W 320
#define H 96
#define FS 96
#define BS 8
#define HW (H * W)
#define NPLANES 9      // 1 + 2*4 levels
#define CH 16          // channels staged per LDS stage (per half)
#define CHB 48         // channels per half (FS/2)
#define NSTAGES 3      // CHB / CH
#define PADW 328       // 4 guard + 320 + 4 guard
#define NTHREADS 640   // 10 waves: two 320-thread channel-halves

// min-waves=4 -> compiler VGPR cap 64 (empirical cap = 256/min_waves).
// Live state ~50 VGPR: fits, NO SPILL; actual usage <=64 still lets HW run
// 8 waves/SIMD. (·,8) forced cap 32 and spilled st[]/a[] -> ~94 MB scratch
// writes per launch (R3/R4 regression).
__global__ __launch_bounds__(NTHREADS, 4)
void cost_volume_kernel(const float* __restrict__ f1,
                        const float* __restrict__ f2,
                        float* __restrict__ out)
{
    __shared__ float sh[2][CH * PADW];  // 41,984 B -> 3 blocks/CU = 126 KB

    const int t   = threadIdx.x;
    const int h   = (t >= 320) ? 1 : 0;   // channel-half
    const int u   = t - h * 320;          // lane within half = column xi
    const int row = blockIdx.x;           // (b, y)
    const int b   = row / H;
    const int y   = row % H;
    const int ch0 = h * CHB;

    // Zero the +-4 per-channel guards of this half's buffer (write-once;
    // staged region [4,324) never touches them).
    if (u < CH * 8) {
        const int c = u >> 3, g = u & 7;
        sh[h][c * PADW + (g < 4 ? g : 320 + g)] = 0.0f;
    }

    const float* f1base = f1 + (((size_t)b * FS) * H + y) * W;
    const float* f2base = f2 + (((size_t)b * FS) * H + y) * W;

    float acc[NPLANES];
#pragma unroll
    for (int p = 0; p < NPLANES; ++p) acc[p] = 0.0f;

    const int xi = u;                // column owned by this thread
    const int sc = u / 20;           // staged channel 0..15 (16 ch x 20 lanes)
    const int sp = u - sc * 20;      // quad slot 0..19 (80 quads per channel)

    // software pipeline: stage-0 f2 quads in registers (4 x float4 = 16 VGPR)
    float4 st[4];
    {
        const float* f2s = f2base + (size_t)(ch0 + sc) * HW;
#pragma unroll
        for (int k = 0; k < 4; ++k)
            st[k] = *(const float4*)(f2s + 4 * (sp + 20 * k));
    }

    for (int s = 0; s < NSTAGES; ++s) {
        __syncthreads();             // prev-stage readers done (covers guards too)
#pragma unroll
        for (int k = 0; k < 4; ++k)
            *(float4*)(&sh[h][sc * PADW + 4 + 4 * (sp + 20 * k)]) = st[k];
        __syncthreads();

        // prefetch next stage's f2 quads (overlaps compute below)
        if (s + 1 < NSTAGES) {
            const float* f2s = f2base + (size_t)(ch0 + (s + 1) * CH + sc) * HW;
#pragma unroll
            for (int k = 0; k < 4; ++k)
                st[k] = *(const float4*)(f2s + 4 * (sp + 20 * k));
        }

        // compute: 16 channels in two 8-channel chunks (a[8] = 8 VGPR)
        const float* f1s = f1base + (size_t)(ch0 + s * CH) * HW + xi;
#pragma unroll
        for (int cc = 0; cc < 2; ++cc) {
            float a[8];
#pragma unroll
            for (int j = 0; j < 8; ++j)
                a[j] = f1s[(size_t)(cc * 8 + j) * HW];
#pragma unroll
            for (int j = 0; j < 8; ++j) {
                const float* wp = &sh[h][(cc * 8 + j) * PADW + xi];
                // plane p <-> shift i=p-4; f2 col = x+4-p; staged at +4 offset
#pragma unroll
                for (int p = 0; p < NPLANES; ++p)
                    acc[p] = fmaf(a[j], wp[8 - p], acc[p]);
            }
        }
    }

    // ---- combine halves through LDS (no global atomics) ----
    __syncthreads();                 // all compute reads of sh done
    float* red = &sh[1][0];          // 9*320 = 2880 floats fits in 5248
    if (h == 1) {
#pragma unroll
        for (int p = 0; p < NPLANES; ++p)
            red[p * 320 + u] = acc[p];
    }
    __syncthreads();
    if (h == 0) {
        const float scale = 1.0f / (float)FS;
        float* orow = out + (((size_t)b * NPLANES) * H + y) * W + xi;
#pragma unroll
        for (int p = 0; p < NPLANES; ++p)
            orow[(size_t)p * HW] = (acc[p] + red[p * 320 + u]) * scale;
    }
}

extern "C" void kernel_launch(void* const* d_in, const int* in_sizes, int n_in,
                              void* d_out, int out_size, void* d_ws, size_t ws_size,
                              hipStream_t stream) {
    (void)in_sizes; (void)n_in; (void)d_ws; (void)ws_size; (void)out_size;
    const float* f1 = (const float*)d_in[0];
    const float* f2 = (const float*)d_in[1];
    float* out = (float*)d_out;

    dim3 grid(BS * H);       // 768 blocks = 3 per CU x 10 waves = 30 waves/CU
    dim3 block(NTHREADS);
    cost_volume_kernel<<<grid, block, 0, stream>>>(f1, f2, out);
}

// Round 6
// 209.093 us; speedup vs baseline: 1.1136x; 1.1136x over previous
//
#include <hip/hip_runtime.h>

#define W 320
#define H 96
#define FS 96
#define BS 8
#define HW (H * W)
#define NPLANES 9      // 1 + 2*4 levels
#define CH 16          // channels staged per LDS stage (per half)
#define CHB 48         // channels per half (FS/2)
#define NSTAGES 3      // CHB / CH
#define PADW 328       // 4 guard + 320 + 4 guard
#define NTHREADS 640   // 10 waves: two 320-thread channel-halves

// NOTE (R2-R5 post-mortems): any register prefetch array (st[4] float4) held
// live across the stage loop goes to SCRATCH despite VGPR headroom ->
// ~94 MB/launch of spill traffic (WRITE_SIZE 86-97 MB vs 8.6 MB ideal).
// R1-style direct load->LDS staging measured clean (WRITE 8.6 MB). Keep it.
__global__ __launch_bounds__(NTHREADS, 4)   // VGPR cap 64; usage ~32
void cost_volume_kernel(const float* __restrict__ f1,
                        const float* __restrict__ f2,
                        float* __restrict__ out)
{
    __shared__ float sh[2][CH * PADW];  // 41,984 B -> 3 blocks/CU = 126 KB

    const int t   = threadIdx.x;
    const int h   = (t >= 320) ? 1 : 0;   // channel-half
    const int u   = t - h * 320;          // lane within half = column xi
    const int row = blockIdx.x;           // (b, y)
    const int b   = row / H;
    const int y   = row % H;
    const int ch0 = h * CHB;

    // Zero the +-4 per-channel guards of this half's buffer (write-once;
    // staged region [4,324) never touches them).
    if (u < CH * 8) {
        const int c = u >> 3, g = u & 7;
        sh[h][c * PADW + (g < 4 ? g : 320 + g)] = 0.0f;
    }

    const float* f1base = f1 + (((size_t)b * FS) * H + y) * W;
    const float* f2base = f2 + (((size_t)b * FS) * H + y) * W;

    float acc[NPLANES];
#pragma unroll
    for (int p = 0; p < NPLANES; ++p) acc[p] = 0.0f;

    const int xi = u;                // column owned by this thread
    const int sc = u / 20;           // staged channel 0..15 (16 ch x 20 lanes)
    const int sp = u - sc * 20;      // quad slot 0..19 (80 quads per channel)

    for (int s = 0; s < NSTAGES; ++s) {
        __syncthreads();             // prev-stage readers done (covers guards too)

        // Direct global -> LDS staging (no register-resident array: the four
        // loads issue back-to-back, one waitcnt, four ds_write_b128).
        const float* f2s = f2base + (size_t)(ch0 + s * CH + sc) * HW;
#pragma unroll
        for (int k = 0; k < 4; ++k) {
            const float4 v = *(const float4*)(f2s + 4 * (sp + 20 * k));
            *(float4*)(&sh[h][sc * PADW + 4 + 4 * (sp + 20 * k)]) = v;
        }
        __syncthreads();

        // compute: 16 channels in two 8-channel chunks (a[8] = 8 VGPR,
        // consumed immediately -> not live across barriers)
        const float* f1s = f1base + (size_t)(ch0 + s * CH) * HW + xi;
#pragma unroll
        for (int cc = 0; cc < 2; ++cc) {
            float a[8];
#pragma unroll
            for (int j = 0; j < 8; ++j)
                a[j] = f1s[(size_t)(cc * 8 + j) * HW];
#pragma unroll
            for (int j = 0; j < 8; ++j) {
                const float* wp = &sh[h][(cc * 8 + j) * PADW + xi];
                // plane p <-> shift i=p-4; f2 col = x+4-p; staged at +4 offset
#pragma unroll
                for (int p = 0; p < NPLANES; ++p)
                    acc[p] = fmaf(a[j], wp[8 - p], acc[p]);
            }
        }
    }

    // ---- combine halves through LDS (no global atomics) ----
    __syncthreads();                 // all compute reads of sh done
    float* red = &sh[1][0];          // 9*320 = 2880 floats fits in 5248
    if (h == 1) {
#pragma unroll
        for (int p = 0; p < NPLANES; ++p)
            red[p * 320 + u] = acc[p];
    }
    __syncthreads();
    if (h == 0) {
        const float scale = 1.0f / (float)FS;
        float* orow = out + (((size_t)b * NPLANES) * H + y) * W + xi;
#pragma unroll
        for (int p = 0; p < NPLANES; ++p)
            orow[(size_t)p * HW] = (acc[p] + red[p * 320 + u]) * scale;
    }
}

extern "C" void kernel_launch(void* const* d_in, const int* in_sizes, int n_in,
                              void* d_out, int out_size, void* d_ws, size_t ws_size,
                              hipStream_t stream) {
    (void)in_sizes; (void)n_in; (void)d_ws; (void)ws_size; (void)out_size;
    const float* f1 = (const float*)d_in[0];
    const float* f2 = (const float*)d_in[1];
    float* out = (float*)d_out;

    dim3 grid(BS * H);       // 768 blocks = 3 per CU x 10 waves = 30 waves/CU
    dim3 block(NTHREADS);
    cost_volume_kernel<<<grid, block, 0, stream>>>(f1, f2, out);
}